// Round 9
// baseline (416.255 us; speedup 1.0000x reference)
//
#include <hip/hip_runtime.h>
#include <hip/hip_bf16.h>

#define S 4096
#define DIM 1536
#define HEADS 12
#define HD 128
#define CHALF 64   // HD/2
#define NQKV 4608  // 3*DIM

typedef unsigned short u16;
typedef unsigned int u32;
typedef __attribute__((ext_vector_type(8))) short bf16x8;
typedef __attribute__((ext_vector_type(4))) float f32x4;
typedef __attribute__((ext_vector_type(16))) float f32x16;

__device__ __forceinline__ u16 f2b(float f) {  // RNE
    u32 u = __float_as_uint(f);
    u32 r = (u + 0x7fffu + ((u >> 16) & 1u)) >> 16;
    return (u16)r;
}
__device__ __forceinline__ float b2f(u16 b) {
    return __uint_as_float(((u32)b) << 16);
}
__device__ __forceinline__ u32 pack2(float a, float b) {
    u32 lo = (__float_as_uint(a) + 0x8000u) >> 16;
    u32 hi = (__float_as_uint(b) + 0x8000u) & 0xffff0000u;
    return lo | hi;
}
__device__ __forceinline__ void gld_lds16(const u16* g, u16* l) {
    __builtin_amdgcn_global_load_lds((const __attribute__((address_space(1))) void*)g,
                                     (__attribute__((address_space(3))) void*)l, 16, 0, 0);
}

// ---------------- fused fp32 -> bf16 conversion (x + 4 weights) + rope tables ----------------
__global__ void k_cvt_all(const float4* __restrict__ x, const float4* __restrict__ wq,
                          const float4* __restrict__ wk, const float4* __restrict__ wv,
                          const float4* __restrict__ wo,
                          ushort4* __restrict__ xb, ushort4* __restrict__ wqkv,
                          ushort4* __restrict__ wob,
                          const float* __restrict__ freqs, const int* __restrict__ grid_sizes,
                          float* __restrict__ cosT, float* __restrict__ sinT) {
    const int N4X = S * DIM / 4, N4W = DIM * DIM / 4;
    const int NCVT = N4X + 4 * N4W;
    int i = blockIdx.x * 256 + threadIdx.x;
    if (i < NCVT) {
        const float4* src; ushort4* dst; int off;
        if (i < N4X) { src = x; dst = xb; off = i; }
        else {
            int j = i - N4X;
            int w = j / N4W; off = j - w * N4W;
            if (w == 0)      { src = wq; dst = wqkv; }
            else if (w == 1) { src = wk; dst = wqkv + N4W; }
            else if (w == 2) { src = wv; dst = wqkv + 2 * N4W; }
            else             { src = wo; dst = wob; }
        }
        float4 v = src[off];
        ushort4 o;
        o.x = f2b(v.x); o.y = f2b(v.y); o.z = f2b(v.z); o.w = f2b(v.w);
        dst[off] = o;
    } else {
        int idx = i - NCVT;
        int s = idx >> 6;
        int ii = idx & 63;
        int H = grid_sizes[1], W = grid_sizes[2];
        int hw = H * W;
        int f = s / hw;
        int rem = s - f * hw;
        int h = rem / W;
        int w = rem - h * W;
        const int f0 = 22, f1 = 21;
        int pos = (ii < f0) ? f : ((ii < f0 + f1) ? h : w);
        float ang = freqs[pos * CHALF + ii];
        cosT[idx] = cosf(ang);
        sinT[idx] = sinf(ang);
    }
}

// ---------------- QKV GEMM: C[M,N] = A[M,K] * W[N,K]^T + bias ----------------
// 32x32x16 MFMA, BK=64, DMA staging with row-XOR chunk swizzle, 128x128 tile.
__global__ __launch_bounds__(256, 3) void k_gemm_qkv(const u16* __restrict__ A, const u16* __restrict__ W,
                                                     const float* __restrict__ b0, const float* __restrict__ b1,
                                                     const float* __restrict__ b2,
                                                     u16* __restrict__ Cout) {
    __shared__ u16 As[128 * 64];
    __shared__ u16 Bs[128 * 64];
    int tid = threadIdx.x;
    int lane = tid & 63, wave = tid >> 6;
    int l31 = lane & 31, hi = lane >> 5;
    int rowBase = blockIdx.y * 128;
    int colBase = blockIdx.x * 128;

    int srow = lane >> 3;
    int scol = (((lane & 7) ^ (srow & 7)) << 3);

    int rw = (wave >> 1) * 64;
    int cw = (wave & 1) * 64;
    int lx = l31 & 7;

    f32x16 acc[2][2] = {};

    for (int kb = 0; kb < DIM; kb += 64) {
        __syncthreads();
#pragma unroll
        for (int it = 0; it < 4; it++) {
            int rb = wave * 32 + it * 8;
            gld_lds16(A + (size_t)(rowBase + rb + srow) * DIM + kb + scol, As + rb * 64);
            gld_lds16(W + (size_t)(colBase + rb + srow) * DIM + kb + scol, Bs + rb * 64);
        }
        __syncthreads();

#pragma unroll
        for (int kk = 0; kk < 4; kk++) {
            int chk = ((kk * 2 + hi) ^ lx) << 3;
            bf16x8 af[2], bf[2];
#pragma unroll
            for (int mi = 0; mi < 2; mi++)
                af[mi] = *(const bf16x8*)(As + (rw + mi * 32 + l31) * 64 + chk);
#pragma unroll
            for (int ni = 0; ni < 2; ni++)
                bf[ni] = *(const bf16x8*)(Bs + (cw + ni * 32 + l31) * 64 + chk);
#pragma unroll
            for (int mi = 0; mi < 2; mi++)
#pragma unroll
                for (int ni = 0; ni < 2; ni++)
                    acc[mi][ni] = __builtin_amdgcn_mfma_f32_32x32x16_bf16(af[mi], bf[ni], acc[mi][ni], 0, 0, 0);
        }
    }

#pragma unroll
    for (int mi = 0; mi < 2; mi++) {
#pragma unroll
        for (int ni = 0; ni < 2; ni++) {
            int col = colBase + cw + ni * 32 + l31;
            int third = colBase / DIM;
            const float* bp = (third == 0) ? b0 : ((third == 1) ? b1 : b2);
            float bv = bp[col - third * DIM];
#pragma unroll
            for (int g = 0; g < 16; g++) {
                int row = rowBase + rw + mi * 32 + (g & 3) + 8 * (g >> 2) + 4 * hi;
                Cout[(size_t)row * NQKV + col] = f2b(acc[mi][ni][g] + bv);
            }
        }
    }
}

// ---------------- Wo GEMM with fused split-K combine ----------------
// out[M,DIM] = combine(O0,O1;lT)[M,DIM] * Wo[DIM,DIM]^T + bo.  128x64 tile, BK=64.
// A staged manually (combine on the fly, row-XOR swizzled LDS); B staged via DMA.
// Head for the K-chunk is uniform per iter: h = kb>>7 (64 | 128).
__global__ __launch_bounds__(256, 3) void k_gemm_wo(const u16* __restrict__ O0, const u16* __restrict__ O1,
                                                    const float* __restrict__ lT,
                                                    const u16* __restrict__ W, const float* __restrict__ bias,
                                                    float* __restrict__ Cout) {
    __shared__ u16 As[128 * 64];
    __shared__ u16 Bs[64 * 64];
    int tid = threadIdx.x;
    int lane = tid & 63, wave = tid >> 6;
    int l31 = lane & 31, hi = lane >> 5;
    int rowBase = blockIdx.y * 128;
    int colBase = blockIdx.x * 64;

    int srow = lane >> 3;
    int scol = (((lane & 7) ^ (srow & 7)) << 3);

    int arow = tid >> 1, ahalf = tid & 1;     // A staging: 1 row per 2 threads, 32 cols each
    int aqrow = rowBase + arow;

    int rw = wave * 32;
    int lx = l31 & 7;

    f32x16 acc[2] = {};

    for (int kb = 0; kb < DIM; kb += 64) {
        int h = kb >> 7;
        float l0 = lT[(size_t)h * S + aqrow];
        float l1 = lT[(size_t)(HEADS + h) * S + aqrow];
        float inv = 1.0f / (l0 + l1);
        float c0 = l0 * inv, c1 = l1 * inv;
        __syncthreads();
        // B via DMA
#pragma unroll
        for (int it = 0; it < 2; it++) {
            int rb = wave * 16 + it * 8;
            gld_lds16(W + (size_t)(colBase + rb + srow) * DIM + kb + scol, Bs + rb * 64);
        }
        // A manual with combine
#pragma unroll
        for (int jj = 0; jj < 4; jj++) {
            int j = ahalf * 4 + jj;
            uint4 u0 = *(const uint4*)(O0 + (size_t)aqrow * DIM + kb + j * 8);
            uint4 u1 = *(const uint4*)(O1 + (size_t)aqrow * DIM + kb + j * 8);
            const u16* a = (const u16*)&u0;
            const u16* b = (const u16*)&u1;
            u32 w4[4];
#pragma unroll
            for (int t = 0; t < 4; t++) {
                float v0 = c0 * b2f(a[2 * t]) + c1 * b2f(b[2 * t]);
                float v1 = c0 * b2f(a[2 * t + 1]) + c1 * b2f(b[2 * t + 1]);
                w4[t] = (u32)f2b(v0) | ((u32)f2b(v1) << 16);
            }
            *(uint4*)(As + arow * 64 + ((j ^ (arow & 7)) << 3)) = *(uint4*)w4;
        }
        __syncthreads();

#pragma unroll
        for (int kk = 0; kk < 4; kk++) {
            int chk = ((kk * 2 + hi) ^ lx) << 3;
            bf16x8 af = *(const bf16x8*)(As + (rw + l31) * 64 + chk);
            bf16x8 bf0 = *(const bf16x8*)(Bs + l31 * 64 + chk);
            bf16x8 bf1 = *(const bf16x8*)(Bs + (32 + l31) * 64 + chk);
            acc[0] = __builtin_amdgcn_mfma_f32_32x32x16_bf16(af, bf0, acc[0], 0, 0, 0);
            acc[1] = __builtin_amdgcn_mfma_f32_32x32x16_bf16(af, bf1, acc[1], 0, 0, 0);
        }
    }

#pragma unroll
    for (int ni = 0; ni < 2; ni++) {
        int col = colBase + ni * 32 + l31;
        float bv = bias[col];
#pragma unroll
        for (int g = 0; g < 16; g++) {
            int row = rowBase + rw + (g & 3) + 8 * (g >> 2) + 4 * hi;
            Cout[(size_t)row * DIM + col] = acc[ni][g] + bv;
        }
    }
}

// ---------------- RMSNorm + RoPE, fused q & k (grid.y selects) ----------------
__global__ __launch_bounds__(256) void k_normrope(u16* __restrict__ qkvp, const float* __restrict__ gq,
                                                  const float* __restrict__ gk,
                                                  const float* __restrict__ cosT, const float* __restrict__ sinT,
                                                  float qscale) {
    int s = blockIdx.x;
    int which = blockIdx.y;
    const float* g = which ? gk : gq;
    float scale = which ? 1.0f : qscale;
    int tid = threadIdx.x;
    int lane = tid & 63, wave = tid >> 6;
    u32* row = (u32*)(qkvp + (size_t)s * NQKV + which * DIM);

    int w0 = tid, w1 = tid + 256, w2 = tid + 512;
    u32 p0 = row[w0], p1 = row[w1], p2 = row[w2];
    float e0 = b2f(p0 & 0xffff), o0 = b2f(p0 >> 16);
    float e1 = b2f(p1 & 0xffff), o1 = b2f(p1 >> 16);
    float e2 = b2f(p2 & 0xffff), o2 = b2f(p2 >> 16);
    float ss = e0 * e0 + o0 * o0 + e1 * e1 + o1 * o1 + e2 * e2 + o2 * o2;

    __shared__ float wsum[4];
    for (int off = 32; off; off >>= 1) ss += __shfl_down(ss, off);
    if (lane == 0) wsum[wave] = ss;
    __syncthreads();
    float tot = wsum[0] + wsum[1] + wsum[2] + wsum[3];
    float r = rsqrtf(tot * (1.0f / DIM) + 1e-6f) * scale;

    const float* cr = cosT + (size_t)s * CHALF;
    const float* sr = sinT + (size_t)s * CHALF;
#pragma unroll
    for (int j = 0; j < 3; j++) {
        int p = (j == 0) ? w0 : (j == 1) ? w1 : w2;
        float e = (j == 0) ? e0 : (j == 1) ? e1 : e2;
        float o = (j == 0) ? o0 : (j == 1) ? o1 : o2;
        int i = p & 63;
        float c = cr[i], sn = sr[i];
        e = e * r * g[2 * p];
        o = o * r * g[2 * p + 1];
        float ne = e * c - o * sn;
        float no = e * sn + o * c;
        row[p] = (u32)f2b(ne) | ((u32)f2b(no) << 16);
    }
}

// ---------------- transpose v-slice of qkv -> vt[DIM][S], with key-permutation ----------------
__global__ void k_transpose(const u16* __restrict__ src, u16* __restrict__ dst) {
    __shared__ u16 t[32][33];
    int bx = blockIdx.x;
    int by = blockIdx.y;
    int tx = threadIdx.x, ty = threadIdx.y;
#pragma unroll
    for (int i = 0; i < 4; i++)
        t[ty + i * 8][tx] = src[(size_t)(by * 32 + ty + i * 8) * NQKV + bx * 32 + tx];
    __syncthreads();
    int txp = (tx & ~12) | ((tx & 4) << 1) | ((tx & 8) >> 1);
#pragma unroll
    for (int i = 0; i < 4; i++)
        dst[(size_t)(bx * 32 + ty + i * 8) * S + by * 32 + txp] = t[tx][ty + i * 8];
}

// ---------------- flash attention: 32x32x16 MFMA, no-max softmax, split-K/2 ----------------
__global__ __launch_bounds__(256, 3) void k_attn(const u16* __restrict__ qkv, const u16* __restrict__ vt,
                                                 u16* __restrict__ O0, u16* __restrict__ O1,
                                                 float* __restrict__ lT,
                                                 const int* __restrict__ seq_lens) {
    int bx = blockIdx.x;
    int xcd = bx & 7, slot = bx >> 3;
    int hp = xcd * 3 + (slot >> 5);
    int h = (hp >= HEADS) ? hp - HEADS : hp;
    int p = (hp >= HEADS) ? 1 : 0;
    int q0 = (slot & 31) * 128;
    int kh0 = p * (S / 2);
    int tid = threadIdx.x;
    int lane = tid & 63, wave = tid >> 6;
    int l31 = lane & 31, hi = lane >> 5;
    int seqlen = seq_lens[0];
    u16* Op = p ? O1 : O0;

    __shared__ u16 Ks[64 * 136];
    __shared__ u16 Vs[128 * 88];

    int qrow = q0 + wave * 32 + l31;
    bf16x8 qf[8];
#pragma unroll
    for (int c = 0; c < 8; c++)
        qf[c] = *(const bf16x8*)(qkv + (size_t)qrow * NQKV + h * HD + c * 16 + hi * 8);

    f32x16 o_acc[4] = {};
    float lsum = 0.f;

    for (int kt = 0; kt < S / 2; kt += 64) {
        int kbase = kh0 + kt;
        __syncthreads();
        {
            int r = tid >> 2, cc = (tid & 3) * 32;
#pragma unroll
            for (int u = 0; u < 4; u++) {
                uint4 kv = *(const uint4*)(qkv + (size_t)(kbase + r) * NQKV + DIM + h * HD + cc + u * 8);
                *(uint4*)(Ks + r * 136 + cc + u * 8) = kv;
            }
            int dr = tid >> 3, dc = (tid & 7) * 8;
#pragma unroll
            for (int it = 0; it < 4; it++)
                *(uint4*)(Vs + (dr + it * 32) * 88 + dc) =
                    *(const uint4*)(vt + (size_t)(h * HD + dr + it * 32) * S + kbase + dc);
        }
        __syncthreads();

        f32x16 sc0 = {}, sc1 = {};
#pragma unroll
        for (int c = 0; c < 8; c++) {
            bf16x8 kf0 = *(const bf16x8*)(Ks + l31 * 136 + c * 16 + hi * 8);
            bf16x8 kf1 = *(const bf16x8*)(Ks + (32 + l31) * 136 + c * 16 + hi * 8);
            sc0 = __builtin_amdgcn_mfma_f32_32x32x16_bf16(kf0, qf[c], sc0, 0, 0, 0);
            sc1 = __builtin_amdgcn_mfma_f32_32x32x16_bf16(kf1, qf[c], sc1, 0, 0, 0);
        }

        bool tail = (kbase + 64 > seqlen);
        bf16x8 pfrag[4];
#pragma unroll
        for (int b = 0; b < 2; b++) {
            f32x16 s16 = b ? sc1 : sc0;
            u32 pk[4][2];
            if (!tail) {
#pragma unroll
                for (int g = 0; g < 4; g++) {
                    float e0 = __builtin_amdgcn_exp2f(s16[4 * g + 0]);
                    float e1 = __builtin_amdgcn_exp2f(s16[4 * g + 1]);
                    float e2 = __builtin_amdgcn_exp2f(s16[4 * g + 2]);
                    float e3 = __builtin_amdgcn_exp2f(s16[4 * g + 3]);
                    lsum += (e0 + e1) + (e2 + e3);
                    pk[g][0] = pack2(e0, e1);
                    pk[g][1] = pack2(e2, e3);
                }
            } else {
#pragma unroll
                for (int g = 0; g < 4; g++) {
                    float e[4];
#pragma unroll
                    for (int r = 0; r < 4; r++) {
                        int key = kbase + b * 32 + r + 8 * g + 4 * hi;
                        float v = __builtin_amdgcn_exp2f(s16[4 * g + r]);
                        e[r] = (key < seqlen) ? v : 0.f;
                        lsum += e[r];
                    }
                    pk[g][0] = pack2(e[0], e[1]);
                    pk[g][1] = pack2(e[2], e[3]);
                }
            }
            union { u32 u[4]; bf16x8 v; } c0v, c1v;
            c0v.u[0] = pk[0][0]; c0v.u[1] = pk[0][1]; c0v.u[2] = pk[1][0]; c0v.u[3] = pk[1][1];
            c1v.u[0] = pk[2][0]; c1v.u[1] = pk[2][1]; c1v.u[2] = pk[3][0]; c1v.u[3] = pk[3][1];
            pfrag[b * 2 + 0] = c0v.v;
            pfrag[b * 2 + 1] = c1v.v;
        }

#pragma unroll
        for (int db = 0; db < 4; db++) {
#pragma unroll
            for (int c4 = 0; c4 < 4; c4++) {
                bf16x8 vf = *(const bf16x8*)(Vs + (db * 32 + l31) * 88 + c4 * 16 + hi * 8);
                o_acc[db] = __builtin_amdgcn_mfma_f32_32x32x16_bf16(vf, pfrag[c4], o_acc[db], 0, 0, 0);
            }
        }
    }

    float l_all = lsum + __shfl_xor(lsum, 32);
    float linv = 1.0f / l_all;
#pragma unroll
    for (int db = 0; db < 4; db++) {
#pragma unroll
        for (int g = 0; g < 4; g++) {
            int d0 = db * 32 + 8 * g + 4 * hi;
            u16 o4[4];
#pragma unroll
            for (int r = 0; r < 4; r++)
                o4[r] = f2b(o_acc[db][4 * g + r] * linv);
            *(uint2*)(Op + (size_t)qrow * DIM + h * HD + d0) = *(const uint2*)o4;
        }
    }
    if (!hi) lT[((size_t)p * HEADS + h) * S + qrow] = l_all;
}

extern "C" void kernel_launch(void* const* d_in, const int* in_sizes, int n_in,
                              void* d_out, int out_size, void* d_ws, size_t ws_size,
                              hipStream_t stream) {
    const float* x = (const float*)d_in[0];
    const int* seq_lens = (const int*)d_in[1];
    const int* grid_sizes = (const int*)d_in[2];
    const float* freqs = (const float*)d_in[3];
    const float* Wq = (const float*)d_in[5];
    const float* bq = (const float*)d_in[6];
    const float* Wk = (const float*)d_in[7];
    const float* bk = (const float*)d_in[8];
    const float* Wv = (const float*)d_in[9];
    const float* bv = (const float*)d_in[10];
    const float* Wo = (const float*)d_in[11];
    const float* bo = (const float*)d_in[12];
    const float* gq = (const float*)d_in[13];
    const float* gk = (const float*)d_in[14];
    float* out = (float*)d_out;

    char* w = (char*)d_ws;
    u16* xb    = (u16*)w; w += (size_t)S * DIM * 2;
    u16* qkv   = (u16*)w; w += (size_t)S * NQKV * 2;
    u16* Wqkvb = (u16*)w; w += (size_t)3 * DIM * DIM * 2;
    u16* Wob   = (u16*)w; w += (size_t)DIM * DIM * 2;
    u16* ab    = (u16*)w; w += (size_t)S * DIM * 2;   // O-partial 0
    u16* O1    = (u16*)w; w += (size_t)S * DIM * 2;   // O-partial 1
    float* cosT = (float*)w; w += (size_t)S * CHALF * 4;
    float* sinT = (float*)w; w += (size_t)S * CHALF * 4;
    float* lT  = (float*)w; w += (size_t)2 * HEADS * S * 4;
    u16* vt = Wqkvb;  // alias: QKV weights dead after QKV GEMM

    const float qscale = 0.08838834764831845f * 1.44269504088896341f;  // HD^-0.5 * log2(e)

    const int N4X = S * DIM / 4, N4W = DIM * DIM / 4;
    const int NCVT = N4X + 4 * N4W;
    const int NTAB = S * CHALF;
    k_cvt_all<<<(NCVT + NTAB) / 256, 256, 0, stream>>>(
        (const float4*)x, (const float4*)Wq, (const float4*)Wk, (const float4*)Wv, (const float4*)Wo,
        (ushort4*)xb, (ushort4*)Wqkvb, (ushort4*)Wob,
        freqs, grid_sizes, cosT, sinT);

    k_gemm_qkv<<<dim3(NQKV / 128, S / 128), 256, 0, stream>>>(
        xb, Wqkvb, bq, bk, bv, qkv);

    k_normrope<<<dim3(S, 2), 256, 0, stream>>>(qkv, gq, gk, cosT, sinT, qscale);

    k_transpose<<<dim3(DIM / 32, S / 32), dim3(32, 8), 0, stream>>>(qkv + 2 * DIM, vt);

    k_attn<<<dim3(768), 256, 0, stream>>>(qkv, vt, ab, O1, lT, seq_lens);

    k_gemm_wo<<<dim3(DIM / 64, S / 128), 256, 0, stream>>>(
        ab, O1, lT, Wob, bo, out);
}

// Round 10
// 372.751 us; speedup vs baseline: 1.1167x; 1.1167x over previous
//
#include <hip/hip_runtime.h>
#include <hip/hip_bf16.h>

#define S 4096
#define DIM 1536
#define HEADS 12
#define HD 128
#define CHALF 64   // HD/2
#define NQKV 4608  // 3*DIM

typedef unsigned short u16;
typedef unsigned int u32;
typedef __attribute__((ext_vector_type(8))) short bf16x8;
typedef __attribute__((ext_vector_type(4))) float f32x4;
typedef __attribute__((ext_vector_type(16))) float f32x16;

__device__ __forceinline__ u16 f2b(float f) {  // RNE
    u32 u = __float_as_uint(f);
    u32 r = (u + 0x7fffu + ((u >> 16) & 1u)) >> 16;
    return (u16)r;
}
__device__ __forceinline__ float b2f(u16 b) {
    return __uint_as_float(((u32)b) << 16);
}
__device__ __forceinline__ u32 pack2(float a, float b) {
    u32 lo = (__float_as_uint(a) + 0x8000u) >> 16;
    u32 hi = (__float_as_uint(b) + 0x8000u) & 0xffff0000u;
    return lo | hi;
}
__device__ __forceinline__ void gld_lds16(const u16* g, u16* l) {
    __builtin_amdgcn_global_load_lds((const __attribute__((address_space(1))) void*)g,
                                     (__attribute__((address_space(3))) void*)l, 16, 0, 0);
}

// ---------------- fused fp32 -> bf16 conversion (x + 4 weights) + rope tables ----------------
__global__ void k_cvt_all(const float4* __restrict__ x, const float4* __restrict__ wq,
                          const float4* __restrict__ wk, const float4* __restrict__ wv,
                          const float4* __restrict__ wo,
                          ushort4* __restrict__ xb, ushort4* __restrict__ wqkv,
                          ushort4* __restrict__ wob,
                          const float* __restrict__ freqs, const int* __restrict__ grid_sizes,
                          float* __restrict__ cosT, float* __restrict__ sinT) {
    const int N4X = S * DIM / 4, N4W = DIM * DIM / 4;
    const int NCVT = N4X + 4 * N4W;
    int i = blockIdx.x * 256 + threadIdx.x;
    if (i < NCVT) {
        const float4* src; ushort4* dst; int off;
        if (i < N4X) { src = x; dst = xb; off = i; }
        else {
            int j = i - N4X;
            int w = j / N4W; off = j - w * N4W;
            if (w == 0)      { src = wq; dst = wqkv; }
            else if (w == 1) { src = wk; dst = wqkv + N4W; }
            else if (w == 2) { src = wv; dst = wqkv + 2 * N4W; }
            else             { src = wo; dst = wob; }
        }
        float4 v = src[off];
        ushort4 o;
        o.x = f2b(v.x); o.y = f2b(v.y); o.z = f2b(v.z); o.w = f2b(v.w);
        dst[off] = o;
    } else {
        int idx = i - NCVT;
        int s = idx >> 6;
        int ii = idx & 63;
        int H = grid_sizes[1], W = grid_sizes[2];
        int hw = H * W;
        int f = s / hw;
        int rem = s - f * hw;
        int h = rem / W;
        int w = rem - h * W;
        const int f0 = 22, f1 = 21;
        int pos = (ii < f0) ? f : ((ii < f0 + f1) ? h : w);
        float ang = freqs[pos * CHALF + ii];
        cosT[idx] = cosf(ang);
        sinT[idx] = sinf(ang);
    }
}

// ---------------- GEMM: C[M,N] = A[M,K] * W[N,K]^T + bias ----------------
// 32x32x16 MFMA, BK=64, global_load_lds staging with row-XOR chunk swizzle into
// unpadded [rows][64] LDS (source chunk j stored at position j^(row&7); frag reads
// undo the xor -> b128 reads at the 8-cyc wave floor).
// TN=128: wave -> 64x64. TN=64: wave -> 32 rows x 64 cols.
template<int TN, int OUT_BF16, int QKV>
__global__ __launch_bounds__(256, 2) void k_gemm(const u16* __restrict__ A, const u16* __restrict__ W,
                                                 const float* __restrict__ b0, const float* __restrict__ b1,
                                                 const float* __restrict__ b2,
                                                 void* __restrict__ Cout, int N, int K, int ldc) {
    __shared__ u16 As[128 * 64];
    __shared__ u16 Bs[TN * 64];
    int tid = threadIdx.x;
    int lane = tid & 63, wave = tid >> 6;
    int l31 = lane & 31, hi = lane >> 5;
    int rowBase = blockIdx.y * 128;
    int colBase = blockIdx.x * TN;

    int srow = lane >> 3;
    int scol = (((lane & 7) ^ (srow & 7)) << 3);

    constexpr int MI = (TN == 128) ? 2 : 1;
    int rw = (TN == 128) ? ((wave >> 1) * 64) : (wave * 32);
    int cw = (TN == 128) ? ((wave & 1) * 64) : 0;
    int lx = l31 & 7;

    f32x16 acc[MI][2] = {};

    for (int kb = 0; kb < K; kb += 64) {
        __syncthreads();
        {
#pragma unroll
            for (int it = 0; it < 4; it++) {
                int rb = wave * 32 + it * 8;
                gld_lds16(A + (size_t)(rowBase + rb + srow) * K + kb + scol, As + rb * 64);
            }
#pragma unroll
            for (int it = 0; it < (TN == 128 ? 4 : 2); it++) {
                int rb = wave * (TN == 128 ? 32 : 16) + it * 8;
                gld_lds16(W + (size_t)(colBase + rb + srow) * K + kb + scol, Bs + rb * 64);
            }
        }
        __syncthreads();

#pragma unroll
        for (int kk = 0; kk < 4; kk++) {
            int chk = ((kk * 2 + hi) ^ lx) << 3;
            bf16x8 af[MI], bf[2];
#pragma unroll
            for (int mi = 0; mi < MI; mi++)
                af[mi] = *(const bf16x8*)(As + (rw + mi * 32 + l31) * 64 + chk);
#pragma unroll
            for (int ni = 0; ni < 2; ni++)
                bf[ni] = *(const bf16x8*)(Bs + (cw + ni * 32 + l31) * 64 + chk);
#pragma unroll
            for (int mi = 0; mi < MI; mi++)
#pragma unroll
                for (int ni = 0; ni < 2; ni++)
                    acc[mi][ni] = __builtin_amdgcn_mfma_f32_32x32x16_bf16(af[mi], bf[ni], acc[mi][ni], 0, 0, 0);
        }
    }

#pragma unroll
    for (int mi = 0; mi < MI; mi++) {
#pragma unroll
        for (int ni = 0; ni < 2; ni++) {
            int col = colBase + cw + ni * 32 + l31;
            float bv;
            if (QKV) {
                int third = colBase / DIM;
                const float* bp = (third == 0) ? b0 : ((third == 1) ? b1 : b2);
                bv = bp[col - third * DIM];
            } else {
                bv = b0[col];
            }
#pragma unroll
            for (int g = 0; g < 16; g++) {
                int row = rowBase + rw + mi * 32 + (g & 3) + 8 * (g >> 2) + 4 * hi;
                float v = acc[mi][ni][g] + bv;
                if (OUT_BF16)
                    ((u16*)Cout)[(size_t)row * ldc + col] = f2b(v);
                else
                    ((float*)Cout)[(size_t)row * ldc + col] = v;
            }
        }
    }
}

// ---------------- RMSNorm + RoPE, fused q & k (grid.y selects) ----------------
__global__ __launch_bounds__(256) void k_normrope(u16* __restrict__ qkvp, const float* __restrict__ gq,
                                                  const float* __restrict__ gk,
                                                  const float* __restrict__ cosT, const float* __restrict__ sinT,
                                                  float qscale) {
    int s = blockIdx.x;
    int which = blockIdx.y;
    const float* g = which ? gk : gq;
    float scale = which ? 1.0f : qscale;
    int tid = threadIdx.x;
    int lane = tid & 63, wave = tid >> 6;
    u32* row = (u32*)(qkvp + (size_t)s * NQKV + which * DIM);

    int w0 = tid, w1 = tid + 256, w2 = tid + 512;
    u32 p0 = row[w0], p1 = row[w1], p2 = row[w2];
    float e0 = b2f(p0 & 0xffff), o0 = b2f(p0 >> 16);
    float e1 = b2f(p1 & 0xffff), o1 = b2f(p1 >> 16);
    float e2 = b2f(p2 & 0xffff), o2 = b2f(p2 >> 16);
    float ss = e0 * e0 + o0 * o0 + e1 * e1 + o1 * o1 + e2 * e2 + o2 * o2;

    __shared__ float wsum[4];
    for (int off = 32; off; off >>= 1) ss += __shfl_down(ss, off);
    if (lane == 0) wsum[wave] = ss;
    __syncthreads();
    float tot = wsum[0] + wsum[1] + wsum[2] + wsum[3];
    float r = rsqrtf(tot * (1.0f / DIM) + 1e-6f) * scale;

    const float* cr = cosT + (size_t)s * CHALF;
    const float* sr = sinT + (size_t)s * CHALF;
#pragma unroll
    for (int j = 0; j < 3; j++) {
        int p = (j == 0) ? w0 : (j == 1) ? w1 : w2;
        float e = (j == 0) ? e0 : (j == 1) ? e1 : e2;
        float o = (j == 0) ? o0 : (j == 1) ? o1 : o2;
        int i = p & 63;
        float c = cr[i], sn = sr[i];
        e = e * r * g[2 * p];
        o = o * r * g[2 * p + 1];
        float ne = e * c - o * sn;
        float no = e * sn + o * c;
        row[p] = (u32)f2b(ne) | ((u32)f2b(no) << 16);
    }
}

// ---------------- transpose v-slice of qkv -> vt[DIM][S], with key-permutation ----------------
__global__ void k_transpose(const u16* __restrict__ src, u16* __restrict__ dst) {
    __shared__ u16 t[32][33];
    int bx = blockIdx.x;
    int by = blockIdx.y;
    int tx = threadIdx.x, ty = threadIdx.y;
#pragma unroll
    for (int i = 0; i < 4; i++)
        t[ty + i * 8][tx] = src[(size_t)(by * 32 + ty + i * 8) * NQKV + bx * 32 + tx];
    __syncthreads();
    int txp = (tx & ~12) | ((tx & 4) << 1) | ((tx & 8) >> 1);
#pragma unroll
    for (int i = 0; i < 4; i++)
        dst[(size_t)(bx * 32 + ty + i * 8) * S + by * 32 + txp] = t[tx][ty + i * 8];
}

// ---------------- flash attention: 32x32x16 MFMA, no-max softmax, split-K/2 ----------------
__global__ __launch_bounds__(256, 3) void k_attn(const u16* __restrict__ qkv, const u16* __restrict__ vt,
                                                 u16* __restrict__ O0, u16* __restrict__ O1,
                                                 float* __restrict__ lT,
                                                 const int* __restrict__ seq_lens) {
    int bx = blockIdx.x;
    int xcd = bx & 7, slot = bx >> 3;
    int hp = xcd * 3 + (slot >> 5);
    int h = (hp >= HEADS) ? hp - HEADS : hp;
    int p = (hp >= HEADS) ? 1 : 0;
    int q0 = (slot & 31) * 128;
    int kh0 = p * (S / 2);
    int tid = threadIdx.x;
    int lane = tid & 63, wave = tid >> 6;
    int l31 = lane & 31, hi = lane >> 5;
    int seqlen = seq_lens[0];
    u16* Op = p ? O1 : O0;

    __shared__ u16 Ks[64 * 136];
    __shared__ u16 Vs[128 * 88];

    int qrow = q0 + wave * 32 + l31;
    bf16x8 qf[8];
#pragma unroll
    for (int c = 0; c < 8; c++)
        qf[c] = *(const bf16x8*)(qkv + (size_t)qrow * NQKV + h * HD + c * 16 + hi * 8);

    f32x16 o_acc[4] = {};
    float lsum = 0.f;

    for (int kt = 0; kt < S / 2; kt += 64) {
        int kbase = kh0 + kt;
        __syncthreads();
        {
            int r = tid >> 2, cc = (tid & 3) * 32;
#pragma unroll
            for (int u = 0; u < 4; u++) {
                uint4 kv = *(const uint4*)(qkv + (size_t)(kbase + r) * NQKV + DIM + h * HD + cc + u * 8);
                *(uint4*)(Ks + r * 136 + cc + u * 8) = kv;
            }
            int dr = tid >> 3, dc = (tid & 7) * 8;
#pragma unroll
            for (int it = 0; it < 4; it++)
                *(uint4*)(Vs + (dr + it * 32) * 88 + dc) =
                    *(const uint4*)(vt + (size_t)(h * HD + dr + it * 32) * S + kbase + dc);
        }
        __syncthreads();

        f32x16 sc0 = {}, sc1 = {};
#pragma unroll
        for (int c = 0; c < 8; c++) {
            bf16x8 kf0 = *(const bf16x8*)(Ks + l31 * 136 + c * 16 + hi * 8);
            bf16x8 kf1 = *(const bf16x8*)(Ks + (32 + l31) * 136 + c * 16 + hi * 8);
            sc0 = __builtin_amdgcn_mfma_f32_32x32x16_bf16(kf0, qf[c], sc0, 0, 0, 0);
            sc1 = __builtin_amdgcn_mfma_f32_32x32x16_bf16(kf1, qf[c], sc1, 0, 0, 0);
        }

        bool tail = (kbase + 64 > seqlen);
        bf16x8 pfrag[4];
#pragma unroll
        for (int b = 0; b < 2; b++) {
            f32x16 s16 = b ? sc1 : sc0;
            u32 pk[4][2];
            if (!tail) {
#pragma unroll
                for (int g = 0; g < 4; g++) {
                    float e0 = __builtin_amdgcn_exp2f(s16[4 * g + 0]);
                    float e1 = __builtin_amdgcn_exp2f(s16[4 * g + 1]);
                    float e2 = __builtin_amdgcn_exp2f(s16[4 * g + 2]);
                    float e3 = __builtin_amdgcn_exp2f(s16[4 * g + 3]);
                    lsum += (e0 + e1) + (e2 + e3);
                    pk[g][0] = pack2(e0, e1);
                    pk[g][1] = pack2(e2, e3);
                }
            } else {
#pragma unroll
                for (int g = 0; g < 4; g++) {
                    float e[4];
#pragma unroll
                    for (int r = 0; r < 4; r++) {
                        int key = kbase + b * 32 + r + 8 * g + 4 * hi;
                        float v = __builtin_amdgcn_exp2f(s16[4 * g + r]);
                        e[r] = (key < seqlen) ? v : 0.f;
                        lsum += e[r];
                    }
                    pk[g][0] = pack2(e[0], e[1]);
                    pk[g][1] = pack2(e[2], e[3]);
                }
            }
            union { u32 u[4]; bf16x8 v; } c0v, c1v;
            c0v.u[0] = pk[0][0]; c0v.u[1] = pk[0][1]; c0v.u[2] = pk[1][0]; c0v.u[3] = pk[1][1];
            c1v.u[0] = pk[2][0]; c1v.u[1] = pk[2][1]; c1v.u[2] = pk[3][0]; c1v.u[3] = pk[3][1];
            pfrag[b * 2 + 0] = c0v.v;
            pfrag[b * 2 + 1] = c1v.v;
        }

#pragma unroll
        for (int db = 0; db < 4; db++) {
#pragma unroll
            for (int c4 = 0; c4 < 4; c4++) {
                bf16x8 vf = *(const bf16x8*)(Vs + (db * 32 + l31) * 88 + c4 * 16 + hi * 8);
                o_acc[db] = __builtin_amdgcn_mfma_f32_32x32x16_bf16(vf, pfrag[c4], o_acc[db], 0, 0, 0);
            }
        }
    }

    float l_all = lsum + __shfl_xor(lsum, 32);
    float linv = 1.0f / l_all;
#pragma unroll
    for (int db = 0; db < 4; db++) {
#pragma unroll
        for (int g = 0; g < 4; g++) {
            int d0 = db * 32 + 8 * g + 4 * hi;
            u16 o4[4];
#pragma unroll
            for (int r = 0; r < 4; r++)
                o4[r] = f2b(o_acc[db][4 * g + r] * linv);
            *(uint2*)(Op + (size_t)qrow * DIM + h * HD + d0) = *(const uint2*)o4;
        }
    }
    if (!hi) lT[((size_t)p * HEADS + h) * S + qrow] = l_all;
}

// ---------------- combine split-K partials: O0 = (l0*O0 + l1*O1)/(l0+l1), in place ----------------
__global__ __launch_bounds__(384) void k_combine(u16* __restrict__ O0, const u16* __restrict__ O1,
                                                 const float* __restrict__ lT) {
    int q = blockIdx.x;
    int tid = threadIdx.x;
    int h = tid >> 5;
    size_t base = (size_t)q * DIM + tid * 4;
    float l0 = lT[(size_t)h * S + q];
    float l1 = lT[(size_t)(HEADS + h) * S + q];
    float inv = 1.0f / (l0 + l1);
    float c0 = l0 * inv, c1 = l1 * inv;
    uint2 u0 = *(const uint2*)(O0 + base);
    uint2 u1 = *(const uint2*)(O1 + base);
    const u16* a = (const u16*)&u0;
    const u16* b = (const u16*)&u1;
    u16 o[4];
#pragma unroll
    for (int i = 0; i < 4; i++)
        o[i] = f2b(c0 * b2f(a[i]) + c1 * b2f(b[i]));
    *(uint2*)(O0 + base) = *(uint2*)o;
}

extern "C" void kernel_launch(void* const* d_in, const int* in_sizes, int n_in,
                              void* d_out, int out_size, void* d_ws, size_t ws_size,
                              hipStream_t stream) {
    const float* x = (const float*)d_in[0];
    const int* seq_lens = (const int*)d_in[1];
    const int* grid_sizes = (const int*)d_in[2];
    const float* freqs = (const float*)d_in[3];
    const float* Wq = (const float*)d_in[5];
    const float* bq = (const float*)d_in[6];
    const float* Wk = (const float*)d_in[7];
    const float* bk = (const float*)d_in[8];
    const float* Wv = (const float*)d_in[9];
    const float* bv = (const float*)d_in[10];
    const float* Wo = (const float*)d_in[11];
    const float* bo = (const float*)d_in[12];
    const float* gq = (const float*)d_in[13];
    const float* gk = (const float*)d_in[14];
    float* out = (float*)d_out;

    char* w = (char*)d_ws;
    u16* xb    = (u16*)w; w += (size_t)S * DIM * 2;
    u16* qkv   = (u16*)w; w += (size_t)S * NQKV * 2;
    u16* Wqkvb = (u16*)w; w += (size_t)3 * DIM * DIM * 2;
    u16* Wob   = (u16*)w; w += (size_t)DIM * DIM * 2;
    u16* ab    = (u16*)w; w += (size_t)S * DIM * 2;
    u16* O1    = (u16*)w; w += (size_t)S * DIM * 2;
    float* cosT = (float*)w; w += (size_t)S * CHALF * 4;
    float* sinT = (float*)w; w += (size_t)S * CHALF * 4;
    float* lT  = (float*)w; w += (size_t)2 * HEADS * S * 4;
    u16* vt = Wqkvb;  // alias: QKV weights dead after QKV GEMM

    const float qscale = 0.08838834764831845f * 1.44269504088896341f;  // HD^-0.5 * log2(e)

    const int N4X = S * DIM / 4, N4W = DIM * DIM / 4;
    const int NCVT = N4X + 4 * N4W;
    const int NTAB = S * CHALF;
    k_cvt_all<<<(NCVT + NTAB) / 256, 256, 0, stream>>>(
        (const float4*)x, (const float4*)Wq, (const float4*)Wk, (const float4*)Wv, (const float4*)Wo,
        (ushort4*)xb, (ushort4*)Wqkvb, (ushort4*)Wob,
        freqs, grid_sizes, cosT, sinT);

    k_gemm<128, 1, 1><<<dim3(NQKV / 128, S / 128), 256, 0, stream>>>(
        xb, Wqkvb, bq, bk, bv, qkv, NQKV, DIM, NQKV);

    k_normrope<<<dim3(S, 2), 256, 0, stream>>>(qkv, gq, gk, cosT, sinT, qscale);

    k_transpose<<<dim3(DIM / 32, S / 32), dim3(32, 8), 0, stream>>>(qkv + 2 * DIM, vt);

    k_attn<<<dim3(768), 256, 0, stream>>>(qkv, vt, ab, O1, lT, seq_lens);

    k_combine<<<S, 384, 0, stream>>>(ab, O1, lT);

    k_gemm<64, 0, 0><<<dim3(DIM / 64, S / 128), 256, 0, stream>>>(
        ab, Wob, bo, bo, bo, out, DIM, DIM, DIM);
}

// Round 11
// 370.101 us; speedup vs baseline: 1.1247x; 1.0072x over previous
//
#include <hip/hip_runtime.h>
#include <hip/hip_bf16.h>

#define S 4096
#define DIM 1536
#define HEADS 12
#define HD 128
#define CHALF 64   // HD/2
#define NQKV 4608  // 3*DIM

typedef unsigned short u16;
typedef unsigned int u32;
typedef __attribute__((ext_vector_type(8))) short bf16x8;
typedef __attribute__((ext_vector_type(4))) float f32x4;
typedef __attribute__((ext_vector_type(16))) float f32x16;

__device__ __forceinline__ u16 f2b(float f) {  // RNE
    u32 u = __float_as_uint(f);
    u32 r = (u + 0x7fffu + ((u >> 16) & 1u)) >> 16;
    return (u16)r;
}
__device__ __forceinline__ float b2f(u16 b) {
    return __uint_as_float(((u32)b) << 16);
}
__device__ __forceinline__ u32 pack2(float a, float b) {
    u32 lo = (__float_as_uint(a) + 0x8000u) >> 16;
    u32 hi = (__float_as_uint(b) + 0x8000u) & 0xffff0000u;
    return lo | hi;
}
__device__ __forceinline__ void gld_lds16(const u16* g, u16* l) {
    __builtin_amdgcn_global_load_lds((const __attribute__((address_space(1))) void*)g,
                                     (__attribute__((address_space(3))) void*)l, 16, 0, 0);
}

// ---------------- fused fp32 -> bf16 conversion (x + 4 weights) + rope tables ----------------
__global__ void k_cvt_all(const float4* __restrict__ x, const float4* __restrict__ wq,
                          const float4* __restrict__ wk, const float4* __restrict__ wv,
                          const float4* __restrict__ wo,
                          ushort4* __restrict__ xb, ushort4* __restrict__ wqkv,
                          ushort4* __restrict__ wob,
                          const float* __restrict__ freqs, const int* __restrict__ grid_sizes,
                          float* __restrict__ cosT, float* __restrict__ sinT) {
    const int N4X = S * DIM / 4, N4W = DIM * DIM / 4;
    const int NCVT = N4X + 4 * N4W;
    int i = blockIdx.x * 256 + threadIdx.x;
    if (i < NCVT) {
        const float4* src; ushort4* dst; int off;
        if (i < N4X) { src = x; dst = xb; off = i; }
        else {
            int j = i - N4X;
            int w = j / N4W; off = j - w * N4W;
            if (w == 0)      { src = wq; dst = wqkv; }
            else if (w == 1) { src = wk; dst = wqkv + N4W; }
            else if (w == 2) { src = wv; dst = wqkv + 2 * N4W; }
            else             { src = wo; dst = wob; }
        }
        float4 v = src[off];
        ushort4 o;
        o.x = f2b(v.x); o.y = f2b(v.y); o.z = f2b(v.z); o.w = f2b(v.w);
        dst[off] = o;
    } else {
        int idx = i - NCVT;
        int s = idx >> 6;
        int ii = idx & 63;
        int H = grid_sizes[1], W = grid_sizes[2];
        int hw = H * W;
        int f = s / hw;
        int rem = s - f * hw;
        int h = rem / W;
        int w = rem - h * W;
        const int f0 = 22, f1 = 21;
        int pos = (ii < f0) ? f : ((ii < f0 + f1) ? h : w);
        float ang = freqs[pos * CHALF + ii];
        cosT[idx] = cosf(ang);
        sinT[idx] = sinf(ang);
    }
}

// ---------------- GEMM: C[M,N] = A[M,K] * W[N,K]^T + bias ----------------
// 32x32x16 MFMA, BK=64, global_load_lds staging with row-XOR chunk swizzle into
// unpadded [rows][64] LDS. (256,3): VGPR cap ~170 >> ~120 need, 3 blocks/CU by LDS.
template<int TN, int OUT_BF16, int QKV>
__global__ __launch_bounds__(256, 3) void k_gemm(const u16* __restrict__ A, const u16* __restrict__ W,
                                                 const float* __restrict__ b0, const float* __restrict__ b1,
                                                 const float* __restrict__ b2,
                                                 void* __restrict__ Cout, int N, int K, int ldc) {
    __shared__ u16 As[128 * 64];
    __shared__ u16 Bs[TN * 64];
    int tid = threadIdx.x;
    int lane = tid & 63, wave = tid >> 6;
    int l31 = lane & 31, hi = lane >> 5;
    int rowBase = blockIdx.y * 128;
    int colBase = blockIdx.x * TN;

    int srow = lane >> 3;
    int scol = (((lane & 7) ^ (srow & 7)) << 3);

    constexpr int MI = (TN == 128) ? 2 : 1;
    int rw = (TN == 128) ? ((wave >> 1) * 64) : (wave * 32);
    int cw = (TN == 128) ? ((wave & 1) * 64) : 0;
    int lx = l31 & 7;

    f32x16 acc[MI][2] = {};

    for (int kb = 0; kb < K; kb += 64) {
        __syncthreads();
        {
#pragma unroll
            for (int it = 0; it < 4; it++) {
                int rb = wave * 32 + it * 8;
                gld_lds16(A + (size_t)(rowBase + rb + srow) * K + kb + scol, As + rb * 64);
            }
#pragma unroll
            for (int it = 0; it < (TN == 128 ? 4 : 2); it++) {
                int rb = wave * (TN == 128 ? 32 : 16) + it * 8;
                gld_lds16(W + (size_t)(colBase + rb + srow) * K + kb + scol, Bs + rb * 64);
            }
        }
        __syncthreads();

#pragma unroll
        for (int kk = 0; kk < 4; kk++) {
            int chk = ((kk * 2 + hi) ^ lx) << 3;
            bf16x8 af[MI], bf[2];
#pragma unroll
            for (int mi = 0; mi < MI; mi++)
                af[mi] = *(const bf16x8*)(As + (rw + mi * 32 + l31) * 64 + chk);
#pragma unroll
            for (int ni = 0; ni < 2; ni++)
                bf[ni] = *(const bf16x8*)(Bs + (cw + ni * 32 + l31) * 64 + chk);
#pragma unroll
            for (int mi = 0; mi < MI; mi++)
#pragma unroll
                for (int ni = 0; ni < 2; ni++)
                    acc[mi][ni] = __builtin_amdgcn_mfma_f32_32x32x16_bf16(af[mi], bf[ni], acc[mi][ni], 0, 0, 0);
        }
    }

#pragma unroll
    for (int mi = 0; mi < MI; mi++) {
#pragma unroll
        for (int ni = 0; ni < 2; ni++) {
            int col = colBase + cw + ni * 32 + l31;
            float bv;
            if (QKV) {
                int third = colBase / DIM;
                const float* bp = (third == 0) ? b0 : ((third == 1) ? b1 : b2);
                bv = bp[col - third * DIM];
            } else {
                bv = b0[col];
            }
#pragma unroll
            for (int g = 0; g < 16; g++) {
                int row = rowBase + rw + mi * 32 + (g & 3) + 8 * (g >> 2) + 4 * hi;
                float v = acc[mi][ni][g] + bv;
                if (OUT_BF16)
                    ((u16*)Cout)[(size_t)row * ldc + col] = f2b(v);
                else
                    ((float*)Cout)[(size_t)row * ldc + col] = v;
            }
        }
    }
}

// ---------------- RMSNorm + RoPE, fused q & k (grid.y selects) ----------------
__global__ __launch_bounds__(256) void k_normrope(u16* __restrict__ qkvp, const float* __restrict__ gq,
                                                  const float* __restrict__ gk,
                                                  const float* __restrict__ cosT, const float* __restrict__ sinT,
                                                  float qscale) {
    int s = blockIdx.x;
    int which = blockIdx.y;
    const float* g = which ? gk : gq;
    float scale = which ? 1.0f : qscale;
    int tid = threadIdx.x;
    int lane = tid & 63, wave = tid >> 6;
    u32* row = (u32*)(qkvp + (size_t)s * NQKV + which * DIM);

    int w0 = tid, w1 = tid + 256, w2 = tid + 512;
    u32 p0 = row[w0], p1 = row[w1], p2 = row[w2];
    float e0 = b2f(p0 & 0xffff), o0 = b2f(p0 >> 16);
    float e1 = b2f(p1 & 0xffff), o1 = b2f(p1 >> 16);
    float e2 = b2f(p2 & 0xffff), o2 = b2f(p2 >> 16);
    float ss = e0 * e0 + o0 * o0 + e1 * e1 + o1 * o1 + e2 * e2 + o2 * o2;

    __shared__ float wsum[4];
    for (int off = 32; off; off >>= 1) ss += __shfl_down(ss, off);
    if (lane == 0) wsum[wave] = ss;
    __syncthreads();
    float tot = wsum[0] + wsum[1] + wsum[2] + wsum[3];
    float r = rsqrtf(tot * (1.0f / DIM) + 1e-6f) * scale;

    const float* cr = cosT + (size_t)s * CHALF;
    const float* sr = sinT + (size_t)s * CHALF;
#pragma unroll
    for (int j = 0; j < 3; j++) {
        int p = (j == 0) ? w0 : (j == 1) ? w1 : w2;
        float e = (j == 0) ? e0 : (j == 1) ? e1 : e2;
        float o = (j == 0) ? o0 : (j == 1) ? o1 : o2;
        int i = p & 63;
        float c = cr[i], sn = sr[i];
        e = e * r * g[2 * p];
        o = o * r * g[2 * p + 1];
        float ne = e * c - o * sn;
        float no = e * sn + o * c;
        row[p] = (u32)f2b(ne) | ((u32)f2b(no) << 16);
    }
}

// ---------------- transpose v-slice of qkv -> vt[DIM][S], with key-permutation ----------------
__global__ void k_transpose(const u16* __restrict__ src, u16* __restrict__ dst) {
    __shared__ u16 t[32][33];
    int bx = blockIdx.x;
    int by = blockIdx.y;
    int tx = threadIdx.x, ty = threadIdx.y;
#pragma unroll
    for (int i = 0; i < 4; i++)
        t[ty + i * 8][tx] = src[(size_t)(by * 32 + ty + i * 8) * NQKV + bx * 32 + tx];
    __syncthreads();
    int txp = (tx & ~12) | ((tx & 4) << 1) | ((tx & 8) >> 1);
#pragma unroll
    for (int i = 0; i < 4; i++)
        dst[(size_t)(bx * 32 + ty + i * 8) * S + by * 32 + txp] = t[tx][ty + i * 8];
}

// ---------------- flash attention: 32x32x16 MFMA, no-max softmax, split-K/2 ----------------
__global__ __launch_bounds__(256, 3) void k_attn(const u16* __restrict__ qkv, const u16* __restrict__ vt,
                                                 u16* __restrict__ O0, u16* __restrict__ O1,
                                                 float* __restrict__ lT,
                                                 const int* __restrict__ seq_lens) {
    int bx = blockIdx.x;
    int xcd = bx & 7, slot = bx >> 3;
    int hp = xcd * 3 + (slot >> 5);
    int h = (hp >= HEADS) ? hp - HEADS : hp;
    int p = (hp >= HEADS) ? 1 : 0;
    int q0 = (slot & 31) * 128;
    int kh0 = p * (S / 2);
    int tid = threadIdx.x;
    int lane = tid & 63, wave = tid >> 6;
    int l31 = lane & 31, hi = lane >> 5;
    int seqlen = seq_lens[0];
    u16* Op = p ? O1 : O0;

    __shared__ u16 Ks[64 * 136];
    __shared__ u16 Vs[128 * 88];

    int qrow = q0 + wave * 32 + l31;
    bf16x8 qf[8];
#pragma unroll
    for (int c = 0; c < 8; c++)
        qf[c] = *(const bf16x8*)(qkv + (size_t)qrow * NQKV + h * HD + c * 16 + hi * 8);

    f32x16 o_acc[4] = {};
    float lsum = 0.f;

    for (int kt = 0; kt < S / 2; kt += 64) {
        int kbase = kh0 + kt;
        __syncthreads();
        {
            int r = tid >> 2, cc = (tid & 3) * 32;
#pragma unroll
            for (int u = 0; u < 4; u++) {
                uint4 kv = *(const uint4*)(qkv + (size_t)(kbase + r) * NQKV + DIM + h * HD + cc + u * 8);
                *(uint4*)(Ks + r * 136 + cc + u * 8) = kv;
            }
            int dr = tid >> 3, dc = (tid & 7) * 8;
#pragma unroll
            for (int it = 0; it < 4; it++)
                *(uint4*)(Vs + (dr + it * 32) * 88 + dc) =
                    *(const uint4*)(vt + (size_t)(h * HD + dr + it * 32) * S + kbase + dc);
        }
        __syncthreads();

        f32x16 sc0 = {}, sc1 = {};
#pragma unroll
        for (int c = 0; c < 8; c++) {
            bf16x8 kf0 = *(const bf16x8*)(Ks + l31 * 136 + c * 16 + hi * 8);
            bf16x8 kf1 = *(const bf16x8*)(Ks + (32 + l31) * 136 + c * 16 + hi * 8);
            sc0 = __builtin_amdgcn_mfma_f32_32x32x16_bf16(kf0, qf[c], sc0, 0, 0, 0);
            sc1 = __builtin_amdgcn_mfma_f32_32x32x16_bf16(kf1, qf[c], sc1, 0, 0, 0);
        }

        bool tail = (kbase + 64 > seqlen);
        bf16x8 pfrag[4];
#pragma unroll
        for (int b = 0; b < 2; b++) {
            f32x16 s16 = b ? sc1 : sc0;
            u32 pk[4][2];
            if (!tail) {
#pragma unroll
                for (int g = 0; g < 4; g++) {
                    float e0 = __builtin_amdgcn_exp2f(s16[4 * g + 0]);
                    float e1 = __builtin_amdgcn_exp2f(s16[4 * g + 1]);
                    float e2 = __builtin_amdgcn_exp2f(s16[4 * g + 2]);
                    float e3 = __builtin_amdgcn_exp2f(s16[4 * g + 3]);
                    lsum += (e0 + e1) + (e2 + e3);
                    pk[g][0] = pack2(e0, e1);
                    pk[g][1] = pack2(e2, e3);
                }
            } else {
#pragma unroll
                for (int g = 0; g < 4; g++) {
                    float e[4];
#pragma unroll
                    for (int r = 0; r < 4; r++) {
                        int key = kbase + b * 32 + r + 8 * g + 4 * hi;
                        float v = __builtin_amdgcn_exp2f(s16[4 * g + r]);
                        e[r] = (key < seqlen) ? v : 0.f;
                        lsum += e[r];
                    }
                    pk[g][0] = pack2(e[0], e[1]);
                    pk[g][1] = pack2(e[2], e[3]);
                }
            }
            union { u32 u[4]; bf16x8 v; } c0v, c1v;
            c0v.u[0] = pk[0][0]; c0v.u[1] = pk[0][1]; c0v.u[2] = pk[1][0]; c0v.u[3] = pk[1][1];
            c1v.u[0] = pk[2][0]; c1v.u[1] = pk[2][1]; c1v.u[2] = pk[3][0]; c1v.u[3] = pk[3][1];
            pfrag[b * 2 + 0] = c0v.v;
            pfrag[b * 2 + 1] = c1v.v;
        }

#pragma unroll
        for (int db = 0; db < 4; db++) {
#pragma unroll
            for (int c4 = 0; c4 < 4; c4++) {
                bf16x8 vf = *(const bf16x8*)(Vs + (db * 32 + l31) * 88 + c4 * 16 + hi * 8);
                o_acc[db] = __builtin_amdgcn_mfma_f32_32x32x16_bf16(vf, pfrag[c4], o_acc[db], 0, 0, 0);
            }
        }
    }

    float l_all = lsum + __shfl_xor(lsum, 32);
    float linv = 1.0f / l_all;
#pragma unroll
    for (int db = 0; db < 4; db++) {
#pragma unroll
        for (int g = 0; g < 4; g++) {
            int d0 = db * 32 + 8 * g + 4 * hi;
            u16 o4[4];
#pragma unroll
            for (int r = 0; r < 4; r++)
                o4[r] = f2b(o_acc[db][4 * g + r] * linv);
            *(uint2*)(Op + (size_t)qrow * DIM + h * HD + d0) = *(const uint2*)o4;
        }
    }
    if (!hi) lT[((size_t)p * HEADS + h) * S + qrow] = l_all;
}

// ---------------- combine split-K partials: O0 = (l0*O0 + l1*O1)/(l0+l1), in place ----------------
__global__ __launch_bounds__(384) void k_combine(u16* __restrict__ O0, const u16* __restrict__ O1,
                                                 const float* __restrict__ lT) {
    int q = blockIdx.x;
    int tid = threadIdx.x;
    int h = tid >> 5;
    size_t base = (size_t)q * DIM + tid * 4;
    float l0 = lT[(size_t)h * S + q];
    float l1 = lT[(size_t)(HEADS + h) * S + q];
    float inv = 1.0f / (l0 + l1);
    float c0 = l0 * inv, c1 = l1 * inv;
    uint2 u0 = *(const uint2*)(O0 + base);
    uint2 u1 = *(const uint2*)(O1 + base);
    const u16* a = (const u16*)&u0;
    const u16* b = (const u16*)&u1;
    u16 o[4];
#pragma unroll
    for (int i = 0; i < 4; i++)
        o[i] = f2b(c0 * b2f(a[i]) + c1 * b2f(b[i]));
    *(uint2*)(O0 + base) = *(uint2*)o;
}

extern "C" void kernel_launch(void* const* d_in, const int* in_sizes, int n_in,
                              void* d_out, int out_size, void* d_ws, size_t ws_size,
                              hipStream_t stream) {
    const float* x = (const float*)d_in[0];
    const int* seq_lens = (const int*)d_in[1];
    const int* grid_sizes = (const int*)d_in[2];
    const float* freqs = (const float*)d_in[3];
    const float* Wq = (const float*)d_in[5];
    const float* bq = (const float*)d_in[6];
    const float* Wk = (const float*)d_in[7];
    const float* bk = (const float*)d_in[8];
    const float* Wv = (const float*)d_in[9];
    const float* bv = (const float*)d_in[10];
    const float* Wo = (const float*)d_in[11];
    const float* bo = (const float*)d_in[12];
    const float* gq = (const float*)d_in[13];
    const float* gk = (const float*)d_in[14];
    float* out = (float*)d_out;

    char* w = (char*)d_ws;
    u16* xb    = (u16*)w; w += (size_t)S * DIM * 2;
    u16* qkv   = (u16*)w; w += (size_t)S * NQKV * 2;
    u16* Wqkvb = (u16*)w; w += (size_t)3 * DIM * DIM * 2;
    u16* Wob   = (u16*)w; w += (size_t)DIM * DIM * 2;
    u16* ab    = (u16*)w; w += (size_t)S * DIM * 2;
    u16* O1    = (u16*)w; w += (size_t)S * DIM * 2;
    float* cosT = (float*)w; w += (size_t)S * CHALF * 4;
    float* sinT = (float*)w; w += (size_t)S * CHALF * 4;
    float* lT  = (float*)w; w += (size_t)2 * HEADS * S * 4;
    u16* vt = Wqkvb;  // alias: QKV weights dead after QKV GEMM

    const float qscale = 0.08838834764831845f * 1.44269504088896341f;  // HD^-0.5 * log2(e)

    const int N4X = S * DIM / 4, N4W = DIM * DIM / 4;
    const int NCVT = N4X + 4 * N4W;
    const int NTAB = S * CHALF;
    k_cvt_all<<<(NCVT + NTAB) / 256, 256, 0, stream>>>(
        (const float4*)x, (const float4*)Wq, (const float4*)Wk, (const float4*)Wv, (const float4*)Wo,
        (ushort4*)xb, (ushort4*)Wqkvb, (ushort4*)Wob,
        freqs, grid_sizes, cosT, sinT);

    k_gemm<128, 1, 1><<<dim3(NQKV / 128, S / 128), 256, 0, stream>>>(
        xb, Wqkvb, bq, bk, bv, qkv, NQKV, DIM, NQKV);

    k_normrope<<<dim3(S, 2), 256, 0, stream>>>(qkv, gq, gk, cosT, sinT, qscale);

    k_transpose<<<dim3(DIM / 32, S / 32), dim3(32, 8), 0, stream>>>(qkv + 2 * DIM, vt);

    k_attn<<<dim3(768), 256, 0, stream>>>(qkv, vt, ab, O1, lT, seq_lens);

    k_combine<<<S, 384, 0, stream>>>(ab, O1, lT);

    k_gemm<64, 0, 0><<<dim3(DIM / 64, S / 128), 256, 0, stream>>>(
        ab, Wob, bo, bo, bo, out, DIM, DIM, DIM);
}

// Round 12
// 363.552 us; speedup vs baseline: 1.1450x; 1.0180x over previous
//
#include <hip/hip_runtime.h>
#include <hip/hip_bf16.h>

#define S 4096
#define DIM 1536
#define HEADS 12
#define HD 128
#define CHALF 64   // HD/2
#define NQKV 4608  // 3*DIM

typedef unsigned short u16;
typedef unsigned int u32;
typedef __attribute__((ext_vector_type(8))) short bf16x8;
typedef __attribute__((ext_vector_type(4))) float f32x4;
typedef __attribute__((ext_vector_type(16))) float f32x16;

__device__ __forceinline__ u16 f2b(float f) {  // RNE
    u32 u = __float_as_uint(f);
    u32 r = (u + 0x7fffu + ((u >> 16) & 1u)) >> 16;
    return (u16)r;
}
__device__ __forceinline__ float b2f(u16 b) {
    return __uint_as_float(((u32)b) << 16);
}
__device__ __forceinline__ u32 pack2(float a, float b) {
    u32 lo = (__float_as_uint(a) + 0x8000u) >> 16;
    u32 hi = (__float_as_uint(b) + 0x8000u) & 0xffff0000u;
    return lo | hi;
}
__device__ __forceinline__ void gld_lds16(const u16* g, u16* l) {
    __builtin_amdgcn_global_load_lds((const __attribute__((address_space(1))) void*)g,
                                     (__attribute__((address_space(3))) void*)l, 16, 0, 0);
}

// ---------------- fused fp32 -> bf16 conversion (x + 4 weights) + rope tables ----------------
__global__ void k_cvt_all(const float4* __restrict__ x, const float4* __restrict__ wq,
                          const float4* __restrict__ wk, const float4* __restrict__ wv,
                          const float4* __restrict__ wo,
                          ushort4* __restrict__ xb, ushort4* __restrict__ wqkv,
                          ushort4* __restrict__ wob,
                          const float* __restrict__ freqs, const int* __restrict__ grid_sizes,
                          float* __restrict__ cosT, float* __restrict__ sinT) {
    const int N4X = S * DIM / 4, N4W = DIM * DIM / 4;
    const int NCVT = N4X + 4 * N4W;
    int i = blockIdx.x * 256 + threadIdx.x;
    if (i < NCVT) {
        const float4* src; ushort4* dst; int off;
        if (i < N4X) { src = x; dst = xb; off = i; }
        else {
            int j = i - N4X;
            int w = j / N4W; off = j - w * N4W;
            if (w == 0)      { src = wq; dst = wqkv; }
            else if (w == 1) { src = wk; dst = wqkv + N4W; }
            else if (w == 2) { src = wv; dst = wqkv + 2 * N4W; }
            else             { src = wo; dst = wob; }
        }
        float4 v = src[off];
        ushort4 o;
        o.x = f2b(v.x); o.y = f2b(v.y); o.z = f2b(v.z); o.w = f2b(v.w);
        dst[off] = o;
    } else {
        int idx = i - NCVT;
        int s = idx >> 6;
        int ii = idx & 63;
        int H = grid_sizes[1], W = grid_sizes[2];
        int hw = H * W;
        int f = s / hw;
        int rem = s - f * hw;
        int h = rem / W;
        int w = rem - h * W;
        const int f0 = 22, f1 = 21;
        int pos = (ii < f0) ? f : ((ii < f0 + f1) ? h : w);
        float ang = freqs[pos * CHALF + ii];
        cosT[idx] = cosf(ang);
        sinT[idx] = sinf(ang);
    }
}

// ---------------- GEMM: C[M,N] = A[M,K] * W[N,K]^T + bias ----------------
// 32x32x16 MFMA, BK=64, global_load_lds staging with row-XOR chunk swizzle into
// unpadded [rows][64] LDS. (256,3): no spill (need ~145 max < 170 cap), 3+ blocks/CU by LDS.
// TN=192: 2x2 waves, wave = 64 rows x 96 cols (grid 24x32 = 768 = exactly 3/CU).
// TN=128: 2x2 waves, wave = 64x64. TN=64: 4 row-strip waves, 32 rows x 64 cols.
template<int TN, int OUT_BF16, int QKV>
__global__ __launch_bounds__(256, 3) void k_gemm(const u16* __restrict__ A, const u16* __restrict__ W,
                                                 const float* __restrict__ b0, const float* __restrict__ b1,
                                                 const float* __restrict__ b2,
                                                 void* __restrict__ Cout, int N, int K, int ldc) {
    __shared__ u16 As[128 * 64];
    __shared__ u16 Bs[TN * 64];
    int tid = threadIdx.x;
    int lane = tid & 63, wave = tid >> 6;
    int l31 = lane & 31, hi = lane >> 5;
    int rowBase = blockIdx.y * 128;
    int colBase = blockIdx.x * TN;

    int srow = lane >> 3;
    int scol = (((lane & 7) ^ (srow & 7)) << 3);

    constexpr int MI = (TN == 64) ? 1 : 2;
    constexpr int NI = (TN == 192) ? 3 : 2;
    int rw = (TN == 64) ? (wave * 32) : ((wave >> 1) * 64);
    int cw = (TN == 64) ? 0 : ((wave & 1) * (NI * 32));
    int lx = l31 & 7;

    f32x16 acc[MI][NI] = {};

    for (int kb = 0; kb < K; kb += 64) {
        __syncthreads();
        {
#pragma unroll
            for (int it = 0; it < 4; it++) {
                int rb = wave * 32 + it * 8;
                gld_lds16(A + (size_t)(rowBase + rb + srow) * K + kb + scol, As + rb * 64);
            }
#pragma unroll
            for (int it = 0; it < TN / 32; it++) {
                int rb = wave * (TN / 4) + it * 8;
                gld_lds16(W + (size_t)(colBase + rb + srow) * K + kb + scol, Bs + rb * 64);
            }
        }
        __syncthreads();

#pragma unroll
        for (int kk = 0; kk < 4; kk++) {
            int chk = ((kk * 2 + hi) ^ lx) << 3;
            bf16x8 af[MI], bf[NI];
#pragma unroll
            for (int mi = 0; mi < MI; mi++)
                af[mi] = *(const bf16x8*)(As + (rw + mi * 32 + l31) * 64 + chk);
#pragma unroll
            for (int ni = 0; ni < NI; ni++)
                bf[ni] = *(const bf16x8*)(Bs + (cw + ni * 32 + l31) * 64 + chk);
#pragma unroll
            for (int mi = 0; mi < MI; mi++)
#pragma unroll
                for (int ni = 0; ni < NI; ni++)
                    acc[mi][ni] = __builtin_amdgcn_mfma_f32_32x32x16_bf16(af[mi], bf[ni], acc[mi][ni], 0, 0, 0);
        }
    }

#pragma unroll
    for (int mi = 0; mi < MI; mi++) {
#pragma unroll
        for (int ni = 0; ni < NI; ni++) {
            int col = colBase + cw + ni * 32 + l31;
            float bv;
            if (QKV) {
                int third = colBase / DIM;   // 1536 % 192 == 0: blocks never straddle thirds
                const float* bp = (third == 0) ? b0 : ((third == 1) ? b1 : b2);
                bv = bp[col - third * DIM];
            } else {
                bv = b0[col];
            }
#pragma unroll
            for (int g = 0; g < 16; g++) {
                int row = rowBase + rw + mi * 32 + (g & 3) + 8 * (g >> 2) + 4 * hi;
                float v = acc[mi][ni][g] + bv;
                if (OUT_BF16)
                    ((u16*)Cout)[(size_t)row * ldc + col] = f2b(v);
                else
                    ((float*)Cout)[(size_t)row * ldc + col] = v;
            }
        }
    }
}

// ---------------- RMSNorm + RoPE, fused q & k (grid.y selects) ----------------
__global__ __launch_bounds__(256) void k_normrope(u16* __restrict__ qkvp, const float* __restrict__ gq,
                                                  const float* __restrict__ gk,
                                                  const float* __restrict__ cosT, const float* __restrict__ sinT,
                                                  float qscale) {
    int s = blockIdx.x;
    int which = blockIdx.y;
    const float* g = which ? gk : gq;
    float scale = which ? 1.0f : qscale;
    int tid = threadIdx.x;
    int lane = tid & 63, wave = tid >> 6;
    u32* row = (u32*)(qkvp + (size_t)s * NQKV + which * DIM);

    int w0 = tid, w1 = tid + 256, w2 = tid + 512;
    u32 p0 = row[w0], p1 = row[w1], p2 = row[w2];
    float e0 = b2f(p0 & 0xffff), o0 = b2f(p0 >> 16);
    float e1 = b2f(p1 & 0xffff), o1 = b2f(p1 >> 16);
    float e2 = b2f(p2 & 0xffff), o2 = b2f(p2 >> 16);
    float ss = e0 * e0 + o0 * o0 + e1 * e1 + o1 * o1 + e2 * e2 + o2 * o2;

    __shared__ float wsum[4];
    for (int off = 32; off; off >>= 1) ss += __shfl_down(ss, off);
    if (lane == 0) wsum[wave] = ss;
    __syncthreads();
    float tot = wsum[0] + wsum[1] + wsum[2] + wsum[3];
    float r = rsqrtf(tot * (1.0f / DIM) + 1e-6f) * scale;

    const float* cr = cosT + (size_t)s * CHALF;
    const float* sr = sinT + (size_t)s * CHALF;
#pragma unroll
    for (int j = 0; j < 3; j++) {
        int p = (j == 0) ? w0 : (j == 1) ? w1 : w2;
        float e = (j == 0) ? e0 : (j == 1) ? e1 : e2;
        float o = (j == 0) ? o0 : (j == 1) ? o1 : o2;
        int i = p & 63;
        float c = cr[i], sn = sr[i];
        e = e * r * g[2 * p];
        o = o * r * g[2 * p + 1];
        float ne = e * c - o * sn;
        float no = e * sn + o * c;
        row[p] = (u32)f2b(ne) | ((u32)f2b(no) << 16);
    }
}

// ---------------- transpose v-slice of qkv -> vt[DIM][S], with key-permutation ----------------
__global__ void k_transpose(const u16* __restrict__ src, u16* __restrict__ dst) {
    __shared__ u16 t[32][33];
    int bx = blockIdx.x;
    int by = blockIdx.y;
    int tx = threadIdx.x, ty = threadIdx.y;
#pragma unroll
    for (int i = 0; i < 4; i++)
        t[ty + i * 8][tx] = src[(size_t)(by * 32 + ty + i * 8) * NQKV + bx * 32 + tx];
    __syncthreads();
    int txp = (tx & ~12) | ((tx & 4) << 1) | ((tx & 8) >> 1);
#pragma unroll
    for (int i = 0; i < 4; i++)
        dst[(size_t)(bx * 32 + ty + i * 8) * S + by * 32 + txp] = t[tx][ty + i * 8];
}

// ---------------- flash attention: 32x32x16 MFMA, no-max softmax, split-K/2 ----------------
__global__ __launch_bounds__(256, 3) void k_attn(const u16* __restrict__ qkv, const u16* __restrict__ vt,
                                                 u16* __restrict__ O0, u16* __restrict__ O1,
                                                 float* __restrict__ lT,
                                                 const int* __restrict__ seq_lens) {
    int bx = blockIdx.x;
    int xcd = bx & 7, slot = bx >> 3;
    int hp = xcd * 3 + (slot >> 5);
    int h = (hp >= HEADS) ? hp - HEADS : hp;
    int p = (hp >= HEADS) ? 1 : 0;
    int q0 = (slot & 31) * 128;
    int kh0 = p * (S / 2);
    int tid = threadIdx.x;
    int lane = tid & 63, wave = tid >> 6;
    int l31 = lane & 31, hi = lane >> 5;
    int seqlen = seq_lens[0];
    u16* Op = p ? O1 : O0;

    __shared__ u16 Ks[64 * 136];
    __shared__ u16 Vs[128 * 88];

    int qrow = q0 + wave * 32 + l31;
    bf16x8 qf[8];
#pragma unroll
    for (int c = 0; c < 8; c++)
        qf[c] = *(const bf16x8*)(qkv + (size_t)qrow * NQKV + h * HD + c * 16 + hi * 8);

    f32x16 o_acc[4] = {};
    float lsum = 0.f;

    for (int kt = 0; kt < S / 2; kt += 64) {
        int kbase = kh0 + kt;
        __syncthreads();
        {
            int r = tid >> 2, cc = (tid & 3) * 32;
#pragma unroll
            for (int u = 0; u < 4; u++) {
                uint4 kv = *(const uint4*)(qkv + (size_t)(kbase + r) * NQKV + DIM + h * HD + cc + u * 8);
                *(uint4*)(Ks + r * 136 + cc + u * 8) = kv;
            }
            int dr = tid >> 3, dc = (tid & 7) * 8;
#pragma unroll
            for (int it = 0; it < 4; it++)
                *(uint4*)(Vs + (dr + it * 32) * 88 + dc) =
                    *(const uint4*)(vt + (size_t)(h * HD + dr + it * 32) * S + kbase + dc);
        }
        __syncthreads();

        f32x16 sc0 = {}, sc1 = {};
#pragma unroll
        for (int c = 0; c < 8; c++) {
            bf16x8 kf0 = *(const bf16x8*)(Ks + l31 * 136 + c * 16 + hi * 8);
            bf16x8 kf1 = *(const bf16x8*)(Ks + (32 + l31) * 136 + c * 16 + hi * 8);
            sc0 = __builtin_amdgcn_mfma_f32_32x32x16_bf16(kf0, qf[c], sc0, 0, 0, 0);
            sc1 = __builtin_amdgcn_mfma_f32_32x32x16_bf16(kf1, qf[c], sc1, 0, 0, 0);
        }

        bool tail = (kbase + 64 > seqlen);
        bf16x8 pfrag[4];
#pragma unroll
        for (int b = 0; b < 2; b++) {
            f32x16 s16 = b ? sc1 : sc0;
            u32 pk[4][2];
            if (!tail) {
#pragma unroll
                for (int g = 0; g < 4; g++) {
                    float e0 = __builtin_amdgcn_exp2f(s16[4 * g + 0]);
                    float e1 = __builtin_amdgcn_exp2f(s16[4 * g + 1]);
                    float e2 = __builtin_amdgcn_exp2f(s16[4 * g + 2]);
                    float e3 = __builtin_amdgcn_exp2f(s16[4 * g + 3]);
                    lsum += (e0 + e1) + (e2 + e3);
                    pk[g][0] = pack2(e0, e1);
                    pk[g][1] = pack2(e2, e3);
                }
            } else {
#pragma unroll
                for (int g = 0; g < 4; g++) {
                    float e[4];
#pragma unroll
                    for (int r = 0; r < 4; r++) {
                        int key = kbase + b * 32 + r + 8 * g + 4 * hi;
                        float v = __builtin_amdgcn_exp2f(s16[4 * g + r]);
                        e[r] = (key < seqlen) ? v : 0.f;
                        lsum += e[r];
                    }
                    pk[g][0] = pack2(e[0], e[1]);
                    pk[g][1] = pack2(e[2], e[3]);
                }
            }
            union { u32 u[4]; bf16x8 v; } c0v, c1v;
            c0v.u[0] = pk[0][0]; c0v.u[1] = pk[0][1]; c0v.u[2] = pk[1][0]; c0v.u[3] = pk[1][1];
            c1v.u[0] = pk[2][0]; c1v.u[1] = pk[2][1]; c1v.u[2] = pk[3][0]; c1v.u[3] = pk[3][1];
            pfrag[b * 2 + 0] = c0v.v;
            pfrag[b * 2 + 1] = c1v.v;
        }

#pragma unroll
        for (int db = 0; db < 4; db++) {
#pragma unroll
            for (int c4 = 0; c4 < 4; c4++) {
                bf16x8 vf = *(const bf16x8*)(Vs + (db * 32 + l31) * 88 + c4 * 16 + hi * 8);
                o_acc[db] = __builtin_amdgcn_mfma_f32_32x32x16_bf16(vf, pfrag[c4], o_acc[db], 0, 0, 0);
            }
        }
    }

    float l_all = lsum + __shfl_xor(lsum, 32);
    float linv = 1.0f / l_all;
#pragma unroll
    for (int db = 0; db < 4; db++) {
#pragma unroll
        for (int g = 0; g < 4; g++) {
            int d0 = db * 32 + 8 * g + 4 * hi;
            u16 o4[4];
#pragma unroll
            for (int r = 0; r < 4; r++)
                o4[r] = f2b(o_acc[db][4 * g + r] * linv);
            *(uint2*)(Op + (size_t)qrow * DIM + h * HD + d0) = *(const uint2*)o4;
        }
    }
    if (!hi) lT[((size_t)p * HEADS + h) * S + qrow] = l_all;
}

// ---------------- combine split-K partials: O0 = (l0*O0 + l1*O1)/(l0+l1), in place ----------------
__global__ __launch_bounds__(384) void k_combine(u16* __restrict__ O0, const u16* __restrict__ O1,
                                                 const float* __restrict__ lT) {
    int q = blockIdx.x;
    int tid = threadIdx.x;
    int h = tid >> 5;
    size_t base = (size_t)q * DIM + tid * 4;
    float l0 = lT[(size_t)h * S + q];
    float l1 = lT[(size_t)(HEADS + h) * S + q];
    float inv = 1.0f / (l0 + l1);
    float c0 = l0 * inv, c1 = l1 * inv;
    uint2 u0 = *(const uint2*)(O0 + base);
    uint2 u1 = *(const uint2*)(O1 + base);
    const u16* a = (const u16*)&u0;
    const u16* b = (const u16*)&u1;
    u16 o[4];
#pragma unroll
    for (int i = 0; i < 4; i++)
        o[i] = f2b(c0 * b2f(a[i]) + c1 * b2f(b[i]));
    *(uint2*)(O0 + base) = *(uint2*)o;
}

extern "C" void kernel_launch(void* const* d_in, const int* in_sizes, int n_in,
                              void* d_out, int out_size, void* d_ws, size_t ws_size,
                              hipStream_t stream) {
    const float* x = (const float*)d_in[0];
    const int* seq_lens = (const int*)d_in[1];
    const int* grid_sizes = (const int*)d_in[2];
    const float* freqs = (const float*)d_in[3];
    const float* Wq = (const float*)d_in[5];
    const float* bq = (const float*)d_in[6];
    const float* Wk = (const float*)d_in[7];
    const float* bk = (const float*)d_in[8];
    const float* Wv = (const float*)d_in[9];
    const float* bv = (const float*)d_in[10];
    const float* Wo = (const float*)d_in[11];
    const float* bo = (const float*)d_in[12];
    const float* gq = (const float*)d_in[13];
    const float* gk = (const float*)d_in[14];
    float* out = (float*)d_out;

    char* w = (char*)d_ws;
    u16* xb    = (u16*)w; w += (size_t)S * DIM * 2;
    u16* qkv   = (u16*)w; w += (size_t)S * NQKV * 2;
    u16* Wqkvb = (u16*)w; w += (size_t)3 * DIM * DIM * 2;
    u16* Wob   = (u16*)w; w += (size_t)DIM * DIM * 2;
    u16* ab    = (u16*)w; w += (size_t)S * DIM * 2;
    u16* O1    = (u16*)w; w += (size_t)S * DIM * 2;
    float* cosT = (float*)w; w += (size_t)S * CHALF * 4;
    float* sinT = (float*)w; w += (size_t)S * CHALF * 4;
    float* lT  = (float*)w; w += (size_t)2 * HEADS * S * 4;
    u16* vt = Wqkvb;  // alias: QKV weights dead after QKV GEMM

    const float qscale = 0.08838834764831845f * 1.44269504088896341f;  // HD^-0.5 * log2(e)

    const int N4X = S * DIM / 4, N4W = DIM * DIM / 4;
    const int NCVT = N4X + 4 * N4W;
    const int NTAB = S * CHALF;
    k_cvt_all<<<(NCVT + NTAB) / 256, 256, 0, stream>>>(
        (const float4*)x, (const float4*)Wq, (const float4*)Wk, (const float4*)Wv, (const float4*)Wo,
        (ushort4*)xb, (ushort4*)Wqkvb, (ushort4*)Wob,
        freqs, grid_sizes, cosT, sinT);

    // 128x192 tile: grid 24x32 = 768 blocks = exactly 3/CU x 256 CUs (one full round)
    k_gemm<192, 1, 1><<<dim3(NQKV / 192, S / 128), 256, 0, stream>>>(
        xb, Wqkvb, bq, bk, bv, qkv, NQKV, DIM, NQKV);

    k_normrope<<<dim3(S, 2), 256, 0, stream>>>(qkv, gq, gk, cosT, sinT, qscale);

    k_transpose<<<dim3(DIM / 32, S / 32), dim3(32, 8), 0, stream>>>(qkv + 2 * DIM, vt);

    k_attn<<<dim3(768), 256, 0, stream>>>(qkv, vt, ab, O1, lT, seq_lens);

    k_combine<<<S, 384, 0, stream>>>(ab, O1, lT);

    k_gemm<64, 0, 0><<<dim3(DIM / 64, S / 128), 256, 0, stream>>>(
        ab, Wob, bo, bo, bo, out, DIM, DIM, DIM);
}